// Round 1
// baseline (870.244 us; speedup 1.0000x reference)
//
#include <hip/hip_runtime.h>
#include <math.h>

#define B   64
#define N   2048
#define A   512
#define RNN 1024
#define DW  1024
#define DS  1024

__device__ __forceinline__ float wave_reduce_sum(float v) {
    #pragma unroll
    for (int off = 32; off > 0; off >>= 1)
        v += __shfl_down(v, off, 64);
    return v;
}

__device__ __forceinline__ float fast_tanh(float x) {
    // tanh(x) = 1 - 2/(exp(2x)+1); exp via v_exp_f32, rcp via v_rcp_f32.
    // Saturates correctly at +/-1 for |x| large (inf -> rcp=0).
    float e = __builtin_amdgcn_exp2f(x * 2.8853900817779268f); // 2*log2(e)
    return 1.0f - 2.0f * __builtin_amdgcn_rcpf(e + 1.0f);
}

// h_word[b,a] = dot(h[b,:], W[a,:]) + bias[a]
__global__ __launch_bounds__(256) void k_hword(const float* __restrict__ h,
                                               const float* __restrict__ W,
                                               const float* __restrict__ bias,
                                               float* __restrict__ hword) {
    __shared__ float4 hs[RNN / 4];
    const int b   = blockIdx.x;
    const int tid = threadIdx.x;
    const float4* h4 = (const float4*)(h + (size_t)b * RNN);
    for (int i = tid; i < RNN / 4; i += 256) hs[i] = h4[i];
    __syncthreads();
    const int wave = tid >> 6, lane = tid & 63;
    const int a0 = blockIdx.y * 128;
    for (int i = wave; i < 128; i += 4) {
        const int a = a0 + i;
        const float4* w4 = (const float4*)(W + (size_t)a * RNN);
        float acc = 0.f;
        #pragma unroll
        for (int j = 0; j < 4; ++j) {
            const int k4 = lane + 64 * j;
            float4 wv = w4[k4];
            float4 hv = hs[k4];
            acc += wv.x * hv.x + wv.y * hv.y + wv.z * hv.z + wv.w * hv.w;
        }
        acc = wave_reduce_sum(acc);
        if (lane == 0) hword[b * A + a] = acc + bias[a];
    }
}

// scores[b,n] = dot(tanh(p[b,n,:] + hword[b,:]), w_alpha) + b_alpha
// one wave per (b,n) row; 4 rows per block
__global__ __launch_bounds__(256) void k_scores(const float* __restrict__ p,
                                                const float* __restrict__ hword,
                                                const float* __restrict__ walpha,
                                                const float* __restrict__ balpha,
                                                float* __restrict__ scores) {
    const int wave = threadIdx.x >> 6, lane = threadIdx.x & 63;
    const int row  = blockIdx.x * 4 + wave;   // [0, B*N)
    const int b    = row >> 11;               // N = 2048
    const float4* p4 = (const float4*)(p + (size_t)row * A);
    const float4* h4 = (const float4*)(hword + (size_t)b * A);
    const float4* w4 = (const float4*)walpha;
    float acc = 0.f;
    #pragma unroll
    for (int j = 0; j < 2; ++j) {
        const int k4 = lane + 64 * j;         // 128 float4 per row
        float4 pv = p4[k4];
        float4 hv = h4[k4];
        float4 wv = w4[k4];
        acc += fast_tanh(pv.x + hv.x) * wv.x;
        acc += fast_tanh(pv.y + hv.y) * wv.y;
        acc += fast_tanh(pv.z + hv.z) * wv.z;
        acc += fast_tanh(pv.w + hv.w) * wv.w;
    }
    acc = wave_reduce_sum(acc);
    if (lane == 0) scores[row] = acc + balpha[0];
}

// in-place softmax over N per batch row; one block per b
__global__ __launch_bounds__(256) void k_softmax(float* __restrict__ sw) {
    const int b   = blockIdx.x;
    float* row = sw + (size_t)b * N;
    const int tid = threadIdx.x;
    const int wave = tid >> 6, lane = tid & 63;
    float v[8];
    float m = -1e30f;
    #pragma unroll
    for (int i = 0; i < 8; ++i) { v[i] = row[tid + 256 * i]; m = fmaxf(m, v[i]); }
    __shared__ float redm[4];
    #pragma unroll
    for (int off = 32; off > 0; off >>= 1) m = fmaxf(m, __shfl_down(m, off, 64));
    if (lane == 0) redm[wave] = m;
    __syncthreads();
    m = fmaxf(fmaxf(redm[0], redm[1]), fmaxf(redm[2], redm[3]));
    float s = 0.f;
    #pragma unroll
    for (int i = 0; i < 8; ++i) {
        v[i] = __builtin_amdgcn_exp2f((v[i] - m) * 1.4426950408889634f);
        s += v[i];
    }
    s = wave_reduce_sum(s);
    __shared__ float reds[4];
    if (lane == 0) reds[wave] = s;
    __syncthreads();
    s = reds[0] + reds[1] + reds[2] + reds[3];
    const float inv = __builtin_amdgcn_rcpf(s);
    #pragma unroll
    for (int i = 0; i < 8; ++i) row[tid + 256 * i] = v[i] * inv;
}

// out[b, 0:1024] = senti_feats[b,:]; out[b, 1024:2048] = 0  (atomic target)
__global__ __launch_bounds__(256) void k_init_out(const float* __restrict__ senti,
                                                  float* __restrict__ out) {
    const int idx = blockIdx.x * 256 + threadIdx.x;  // float4 index, 32768 total
    const int b = idx >> 9;                          // 512 float4 per out row
    const int j = idx & 511;
    float4 v;
    if (j < 256) v = ((const float4*)senti)[b * 256 + j];
    else         v = make_float4(0.f, 0.f, 0.f, 0.f);
    ((float4*)out)[idx] = v;
}

// out[b, 1024+d] += sum_{n in chunk} weight[b,n] * swf[b,n,d]
__global__ __launch_bounds__(256) void k_pool(const float* __restrict__ swf,
                                              const float* __restrict__ weight,
                                              float* __restrict__ out) {
    const int b  = blockIdx.x;
    const int n0 = blockIdx.y * 128;
    const int t  = threadIdx.x;                 // float4 column index, 256 = DW/4
    const float4* s4 = (const float4*)swf + ((size_t)b * N + n0) * (DW / 4) + t;
    const float* w   = weight + (size_t)b * N + n0;
    float4 acc = make_float4(0.f, 0.f, 0.f, 0.f);
    #pragma unroll 4
    for (int n = 0; n < 128; ++n) {
        const float wv = w[n];
        float4 v = s4[(size_t)n * (DW / 4)];
        acc.x += wv * v.x; acc.y += wv * v.y; acc.z += wv * v.z; acc.w += wv * v.w;
    }
    float* o = out + (size_t)b * (DS + DW) + DS + t * 4;
    atomicAdd(o + 0, acc.x);
    atomicAdd(o + 1, acc.y);
    atomicAdd(o + 2, acc.z);
    atomicAdd(o + 3, acc.w);
}

extern "C" void kernel_launch(void* const* d_in, const int* in_sizes, int n_in,
                              void* d_out, int out_size, void* d_ws, size_t ws_size,
                              hipStream_t stream) {
    const float* h      = (const float*)d_in[0];
    const float* senti  = (const float*)d_in[1];
    const float* swf    = (const float*)d_in[2];  // [B, N, DW]
    const float* p      = (const float*)d_in[3];  // [B, N, A]
    const float* W      = (const float*)d_in[4];  // [A, RNN]
    const float* bh     = (const float*)d_in[5];  // [A]
    const float* walpha = (const float*)d_in[6];  // [A]
    const float* balpha = (const float*)d_in[7];  // [1]
    float* out = (float*)d_out;
    float* ws  = (float*)d_ws;

    float* hword = ws;                // B*A   = 32768 floats
    float* sw    = ws + B * A;        // B*N   = 131072 floats (scores -> weights)

    k_hword  <<<dim3(B, 4),       256, 0, stream>>>(h, W, bh, hword);
    k_scores <<<dim3(B * N / 4),  256, 0, stream>>>(p, hword, walpha, balpha, sw);
    k_softmax<<<dim3(B),          256, 0, stream>>>(sw);
    k_init_out<<<dim3(B * (DS + DW) / 1024), 256, 0, stream>>>(senti, out);
    k_pool   <<<dim3(B, 16),      256, 0, stream>>>(swf, sw, out);
}

// Round 2
// 855.127 us; speedup vs baseline: 1.0177x; 1.0177x over previous
//
#include <hip/hip_runtime.h>
#include <math.h>

#define B   64
#define N   2048
#define A   512
#define RNN 1024
#define DW  1024
#define DS  1024
#define NCHUNK 16          // n-chunks in k_pool
#define CHUNK  (N / NCHUNK)

__device__ __forceinline__ float wave_reduce_sum(float v) {
    #pragma unroll
    for (int off = 32; off > 0; off >>= 1)
        v += __shfl_down(v, off, 64);
    return v;
}

__device__ __forceinline__ float fast_tanh(float x) {
    // tanh(x) = 1 - 2/(exp(2x)+1); exp via v_exp_f32, rcp via v_rcp_f32.
    float e = __builtin_amdgcn_exp2f(x * 2.8853900817779268f); // 2*log2(e)
    return 1.0f - 2.0f * __builtin_amdgcn_rcpf(e + 1.0f);
}

// h_word[b,a] = dot(h[b,:], W[a,:]) + bias[a]
__global__ __launch_bounds__(256) void k_hword(const float* __restrict__ h,
                                               const float* __restrict__ W,
                                               const float* __restrict__ bias,
                                               float* __restrict__ hword) {
    __shared__ float4 hs[RNN / 4];
    const int b   = blockIdx.x;
    const int tid = threadIdx.x;
    const float4* h4 = (const float4*)(h + (size_t)b * RNN);
    for (int i = tid; i < RNN / 4; i += 256) hs[i] = h4[i];
    __syncthreads();
    const int wave = tid >> 6, lane = tid & 63;
    const int a0 = blockIdx.y * 128;
    for (int i = wave; i < 128; i += 4) {
        const int a = a0 + i;
        const float4* w4 = (const float4*)(W + (size_t)a * RNN);
        float acc = 0.f;
        #pragma unroll
        for (int j = 0; j < 4; ++j) {
            const int k4 = lane + 64 * j;
            float4 wv = w4[k4];
            float4 hv = hs[k4];
            acc += wv.x * hv.x + wv.y * hv.y + wv.z * hv.z + wv.w * hv.w;
        }
        acc = wave_reduce_sum(acc);
        if (lane == 0) hword[b * A + a] = acc + bias[a];
    }
}

// scores[b,n] = dot(tanh(p[b,n,:] + hword[b,:]), w_alpha) + b_alpha
// one wave per (b,n) row; 4 rows per block
__global__ __launch_bounds__(256) void k_scores(const float* __restrict__ p,
                                                const float* __restrict__ hword,
                                                const float* __restrict__ walpha,
                                                const float* __restrict__ balpha,
                                                float* __restrict__ scores) {
    const int wave = threadIdx.x >> 6, lane = threadIdx.x & 63;
    const int row  = blockIdx.x * 4 + wave;   // [0, B*N)
    const int b    = row >> 11;               // N = 2048
    const float4* p4 = (const float4*)(p + (size_t)row * A);
    const float4* h4 = (const float4*)(hword + (size_t)b * A);
    const float4* w4 = (const float4*)walpha;
    float acc = 0.f;
    #pragma unroll
    for (int j = 0; j < 2; ++j) {
        const int k4 = lane + 64 * j;         // 128 float4 per row
        float4 pv = p4[k4];
        float4 hv = h4[k4];
        float4 wv = w4[k4];
        acc += fast_tanh(pv.x + hv.x) * wv.x;
        acc += fast_tanh(pv.y + hv.y) * wv.y;
        acc += fast_tanh(pv.z + hv.z) * wv.z;
        acc += fast_tanh(pv.w + hv.w) * wv.w;
    }
    acc = wave_reduce_sum(acc);
    if (lane == 0) scores[row] = acc + balpha[0];
}

// in-place softmax over N per batch row; one block per b
__global__ __launch_bounds__(256) void k_softmax(float* __restrict__ sw) {
    const int b   = blockIdx.x;
    float* row = sw + (size_t)b * N;
    const int tid = threadIdx.x;
    const int wave = tid >> 6, lane = tid & 63;
    float v[8];
    float m = -1e30f;
    #pragma unroll
    for (int i = 0; i < 8; ++i) { v[i] = row[tid + 256 * i]; m = fmaxf(m, v[i]); }
    __shared__ float redm[4];
    #pragma unroll
    for (int off = 32; off > 0; off >>= 1) m = fmaxf(m, __shfl_down(m, off, 64));
    if (lane == 0) redm[wave] = m;
    __syncthreads();
    m = fmaxf(fmaxf(redm[0], redm[1]), fmaxf(redm[2], redm[3]));
    float s = 0.f;
    #pragma unroll
    for (int i = 0; i < 8; ++i) {
        v[i] = __builtin_amdgcn_exp2f((v[i] - m) * 1.4426950408889634f);
        s += v[i];
    }
    s = wave_reduce_sum(s);
    __shared__ float reds[4];
    if (lane == 0) reds[wave] = s;
    __syncthreads();
    s = reds[0] + reds[1] + reds[2] + reds[3];
    const float inv = __builtin_amdgcn_rcpf(s);
    #pragma unroll
    for (int i = 0; i < 8; ++i) row[tid + 256 * i] = v[i] * inv;
}

// partial[b][c][d] = sum_{n in chunk c} weight[b,n] * swf[b,n,d]
// grid (B, NCHUNK), 256 threads; thread t owns float4 column t. No atomics.
__global__ __launch_bounds__(256) void k_pool(const float* __restrict__ swf,
                                              const float* __restrict__ weight,
                                              float* __restrict__ partial) {
    const int b  = blockIdx.x;
    const int c  = blockIdx.y;
    const int n0 = c * CHUNK;
    const int t  = threadIdx.x;                 // float4 column index, 256 = DW/4
    const float4* s4 = (const float4*)swf + ((size_t)b * N + n0) * (DW / 4) + t;
    const float* w   = weight + (size_t)b * N + n0;
    float4 acc = make_float4(0.f, 0.f, 0.f, 0.f);
    #pragma unroll 4
    for (int n = 0; n < CHUNK; ++n) {
        const float wv = w[n];
        float4 v = s4[(size_t)n * (DW / 4)];
        acc.x += wv * v.x; acc.y += wv * v.y; acc.z += wv * v.z; acc.w += wv * v.w;
    }
    ((float4*)partial)[((size_t)b * NCHUNK + c) * (DW / 4) + t] = acc;
}

// out[b, 0:DS] = senti[b,:]; out[b, DS:DS+DW] = sum_c partial[b][c][:]
// grid (B), 256 threads (= DS/4 = DW/4 float4 lanes)
__global__ __launch_bounds__(256) void k_reduce_concat(const float* __restrict__ senti,
                                                       const float* __restrict__ partial,
                                                       float* __restrict__ out) {
    const int b = blockIdx.x;
    const int t = threadIdx.x;
    float4* o4 = (float4*)out + (size_t)b * ((DS + DW) / 4);
    // senti half
    o4[t] = ((const float4*)senti)[(size_t)b * (DS / 4) + t];
    // word_res half
    const float4* p4 = (const float4*)partial + (size_t)b * NCHUNK * (DW / 4) + t;
    float4 acc = make_float4(0.f, 0.f, 0.f, 0.f);
    #pragma unroll
    for (int c = 0; c < NCHUNK; ++c) {
        float4 v = p4[(size_t)c * (DW / 4)];
        acc.x += v.x; acc.y += v.y; acc.z += v.z; acc.w += v.w;
    }
    o4[DS / 4 + t] = acc;
}

extern "C" void kernel_launch(void* const* d_in, const int* in_sizes, int n_in,
                              void* d_out, int out_size, void* d_ws, size_t ws_size,
                              hipStream_t stream) {
    const float* h      = (const float*)d_in[0];
    const float* senti  = (const float*)d_in[1];
    const float* swf    = (const float*)d_in[2];  // [B, N, DW]
    const float* p      = (const float*)d_in[3];  // [B, N, A]
    const float* W      = (const float*)d_in[4];  // [A, RNN]
    const float* bh     = (const float*)d_in[5];  // [A]
    const float* walpha = (const float*)d_in[6];  // [A]
    const float* balpha = (const float*)d_in[7];  // [1]
    float* out = (float*)d_out;
    float* ws  = (float*)d_ws;

    float* hword   = ws;                          // B*A          = 32768 floats
    float* sw      = hword + B * A;               // B*N          = 131072 floats
    float* partial = sw + B * N;                  // B*NCHUNK*DW  = 1048576 floats

    k_hword        <<<dim3(B, 4),      256, 0, stream>>>(h, W, bh, hword);
    k_scores       <<<dim3(B * N / 4), 256, 0, stream>>>(p, hword, walpha, balpha, sw);
    k_softmax      <<<dim3(B),         256, 0, stream>>>(sw);
    k_pool         <<<dim3(B, NCHUNK), 256, 0, stream>>>(swf, sw, partial);
    k_reduce_concat<<<dim3(B),         256, 0, stream>>>(senti, partial, out);
}